// Round 1
// baseline (725.527 us; speedup 1.0000x reference)
//
#include <hip/hip_runtime.h>
#include <cstdint>

// Algebraic feature expansion: out[B, 696] = concat(x[B,16],
//   prod over all 2-subsets (120 cols), prod over all 3-subsets (560 cols)).
// Pure write-BW-bound: 730 MB out vs 17 MB in. Everything is organized
// around perfectly coalesced float4 nontemporal stores.

#define NCOLS   16
#define NOUT    696          // 16 + C(16,2)=120 + C(16,3)=560
#define RPB     128          // rows per block
#define THREADS 256
#define F4_PER_ROW 174       // 696 / 4
#define F4_PER_BLOCK (RPB * F4_PER_ROW)          // 22272
#define ITERS   (F4_PER_BLOCK / THREADS)         // 87, exact

typedef float vfloat4 __attribute__((ext_vector_type(4)));

// Compile-time table: for each output column, three 5-bit indices into the
// padded row (index 16 = sentinel 1.0f). Order matches itertools.combinations
// lexicographic order exactly: singles(identity) 0..15, then pairs, then triples.
struct Tab { uint32_t v[NOUT]; };
static constexpr Tab make_tab() {
    Tab T{};
    int n = 0;
    for (uint32_t c = 0; c < NCOLS; ++c)
        T.v[n++] = c | (16u << 8) | (16u << 16);
    for (uint32_t i = 0; i < NCOLS; ++i)
        for (uint32_t j = i + 1; j < NCOLS; ++j)
            T.v[n++] = i | (j << 8) | (16u << 16);
    for (uint32_t i = 0; i < NCOLS; ++i)
        for (uint32_t j = i + 1; j < NCOLS; ++j)
            for (uint32_t k = j + 1; k < NCOLS; ++k)
                T.v[n++] = i | (j << 8) | (k << 16);
    return T;
}
__constant__ Tab c_tab = make_tab();

__global__ __launch_bounds__(THREADS) void algebraic_expand_kernel(
        const float* __restrict__ x, float* __restrict__ out, int nrows) {
    // Row stride 17: slot 16 of each row holds the 1.0f sentinel; the odd
    // stride also scatters rows across banks (<=2-way aliasing per wave: free).
    __shared__ float    xs[RPB * 17];
    __shared__ uint4    tab4[F4_PER_ROW];   // table as uint4 -> ds_read_b128, conflict-free

    const int tid = threadIdx.x;
    const int r0  = blockIdx.x * RPB;

    // Stage index table into LDS (696 words, 3 coalesced passes).
    for (int i = tid; i < NOUT; i += THREADS)
        ((uint32_t*)tab4)[i] = c_tab.v[i];

    // Stage x tile (128 rows x 16 cols) into padded LDS; plant sentinels.
    // Read traffic is 2.3% of write traffic — scalar loads are fine here.
    for (int i = tid; i < RPB * 17; i += THREADS) {
        int r = i / 17;              // const-divisor magic mul
        int c = i - r * 17;
        float v = 1.0f;              // sentinel for slot 16
        if (c < NCOLS) {
            int row = r0 + r;
            v = (row < nrows) ? x[row * NCOLS + c] : 0.0f;
        }
        xs[i] = v;
    }
    __syncthreads();

    // Each block owns a contiguous span of 22272 float4 in the output.
    vfloat4* outv = (vfloat4*)out + (long long)r0 * F4_PER_ROW;
    const long long rows_here = (long long)nrows - r0;
    const long long maxe = (rows_here >= RPB ? (long long)RPB : rows_here) * F4_PER_ROW;

    for (int it = 0; it < ITERS; ++it) {
        const int e = it * THREADS + tid;
        if (e >= maxe) return;                         // only hits in a partial tail block
        const int row = (int)((unsigned)e / F4_PER_ROW);   // const-divisor magic mul
        const int c4  = e - row * F4_PER_ROW;
        const float* __restrict__ xr = xs + row * 17;

        const uint4 t = tab4[c4];
        vfloat4 o;
        o.x = xr[t.x & 0x1f] * xr[(t.x >> 8) & 0x1f] * xr[(t.x >> 16) & 0x1f];
        o.y = xr[t.y & 0x1f] * xr[(t.y >> 8) & 0x1f] * xr[(t.y >> 16) & 0x1f];
        o.z = xr[t.z & 0x1f] * xr[(t.z >> 8) & 0x1f] * xr[(t.z >> 16) & 0x1f];
        o.w = xr[t.w & 0x1f] * xr[(t.w >> 8) & 0x1f] * xr[(t.w >> 16) & 0x1f];

        __builtin_nontemporal_store(o, &outv[e]);      // streaming store; out is never re-read
    }
}

extern "C" void kernel_launch(void* const* d_in, const int* in_sizes, int n_in,
                              void* d_out, int out_size, void* d_ws, size_t ws_size,
                              hipStream_t stream) {
    const float* x = (const float*)d_in[0];
    float* out = (float*)d_out;
    const int nrows = in_sizes[0] / NCOLS;             // 262144
    const int blocks = (nrows + RPB - 1) / RPB;        // 2048
    algebraic_expand_kernel<<<blocks, THREADS, 0, stream>>>(x, out, nrows);
}